// Round 2
// baseline (7685.332 us; speedup 1.0000x reference)
//
#include <hip/hip_runtime.h>
#include <hip/hip_bf16.h>
#include <math.h>

// ---------------------------------------------------------------------------
// GCN link-prediction encoder: 6 GCN layers + dot-product decoder.
// norm precompute -> per layer {GEMM, selfloop-init, edge scatter, bias/relu}
// -> decoder.
// ---------------------------------------------------------------------------

__global__ void k_init_deg(float* __restrict__ deg, int n) {
    int i = blockIdx.x * 256 + threadIdx.x;
    if (i < n) deg[i] = 1.0f;  // self-loop weight
}

__global__ void k_accum_deg(const int* __restrict__ col, const float* __restrict__ ew,
                            float* __restrict__ deg, int E) {
    int i = blockIdx.x * 256 + threadIdx.x;
    if (i < E) unsafeAtomicAdd(&deg[col[i]], ew[i]);
}

__global__ void k_dinv(float* __restrict__ deg, int n) {
    int i = blockIdx.x * 256 + threadIdx.x;
    if (i < n) {
        float v = deg[i];
        deg[i] = (v > 0.f) ? rsqrtf(v) : 0.f;
    }
}

__global__ void k_norm(const int* __restrict__ row, const int* __restrict__ col,
                       const float* __restrict__ ew, const float* __restrict__ dinv,
                       float* __restrict__ norm, int E) {
    int i = blockIdx.x * 256 + threadIdx.x;
    if (i < E) norm[i] = dinv[row[i]] * ew[i] * dinv[col[i]];
}

// H = X @ W   (X: [n, IN_C], W: [IN_C, OUT_C] row-major, H: [n, OUT_C])
// 16 rows per block staged in LDS; thread owns one float4 column chunk for
// 16/(256/(OUT_C/4)) rows.
template <int IN_C, int OUT_C>
__global__ __launch_bounds__(256) void k_gemm(
    const float* __restrict__ X, const float* __restrict__ W,
    float* __restrict__ H, int n)
{
    constexpr int C4  = OUT_C / 4;   // float4 chunks per row (32 or 16)
    constexpr int RG  = 256 / C4;    // row groups (8 or 16)
    constexpr int RPT = 16 / RG;     // rows per thread (2 or 1)

    __shared__ float xs[16 * IN_C];
    const int row0 = blockIdx.x * 16;
    const int tid  = threadIdx.x;

    // cooperative load of 16 X rows (float4-vectorized, coalesced)
    {
        const float4* X4  = reinterpret_cast<const float4*>(X + (size_t)row0 * IN_C);
        float4*       xs4 = reinterpret_cast<float4*>(xs);
        constexpr int NLD = 16 * IN_C / 4;
        #pragma unroll
        for (int i = tid; i < NLD; i += 256) {
            int r = i / (IN_C / 4);
            xs4[i] = (row0 + r < n) ? X4[i] : make_float4(0.f, 0.f, 0.f, 0.f);
        }
    }
    __syncthreads();

    const int c4 = tid % C4;
    const int rg = tid / C4;
    const float4* W4 = reinterpret_cast<const float4*>(W);

    float4 acc[RPT];
    #pragma unroll
    for (int j = 0; j < RPT; j++) acc[j] = make_float4(0.f, 0.f, 0.f, 0.f);

    for (int k = 0; k < IN_C; k++) {
        float4 w4 = W4[k * C4 + c4];   // L1-resident after first touch
        #pragma unroll
        for (int j = 0; j < RPT; j++) {
            float xv = xs[(rg + j * RG) * IN_C + k];   // LDS broadcast
            acc[j].x += xv * w4.x;
            acc[j].y += xv * w4.y;
            acc[j].z += xv * w4.z;
            acc[j].w += xv * w4.w;
        }
    }

    float4* H4 = reinterpret_cast<float4*>(H);
    #pragma unroll
    for (int j = 0; j < RPT; j++) {
        int r = row0 + rg + j * RG;
        if (r < n) H4[(size_t)r * C4 + c4] = acc[j];
    }
}

// G[i][c] = dinv[i]^2 * H[i][c]   (self-loop message), float4-vectorized
template <int OC>
__global__ void k_selfloop(const float* __restrict__ H, const float* __restrict__ dinv,
                           float* __restrict__ G, int n)
{
    constexpr int C4 = OC / 4;
    long i = (long)blockIdx.x * 256 + threadIdx.x;   // over n*C4 float4s
    if (i >= (long)n * C4) return;
    int r = (int)(i / C4);
    float d = dinv[r];
    float d2 = d * d;
    float4 h = reinterpret_cast<const float4*>(H)[i];
    reinterpret_cast<float4*>(G)[i] = make_float4(h.x * d2, h.y * d2, h.z * d2, h.w * d2);
}

// G[col[e]] += norm[e] * H[row[e]]  — one wave (64 lanes) per edge
template <int OC>
__global__ __launch_bounds__(256) void k_scatter(
    const float* __restrict__ H, const int* __restrict__ row,
    const int* __restrict__ col, const float* __restrict__ norm,
    float* __restrict__ G, int E)
{
    const int lane = threadIdx.x & 63;
    const int w    = threadIdx.x >> 6;
    long e = (long)blockIdx.x * 4 + w;
    if (e >= E) return;
    int   r  = row[e];
    int   c  = col[e];
    float nm = norm[e];
    if constexpr (OC == 128) {
        float2 v = reinterpret_cast<const float2*>(H + (size_t)r * 128)[lane];
        float* gp = G + (size_t)c * 128 + lane * 2;
        unsafeAtomicAdd(gp,     nm * v.x);
        unsafeAtomicAdd(gp + 1, nm * v.y);
    } else {
        float v = H[(size_t)r * 64 + lane];
        unsafeAtomicAdd(G + (size_t)c * 64 + lane, nm * v);
    }
}

template <bool RELU, int OC>
__global__ void k_bias_act(float* __restrict__ G, const float* __restrict__ b, int n) {
    long i = (long)blockIdx.x * 256 + threadIdx.x;
    if (i < (long)n * OC) {
        float v = G[i] + b[i & (OC - 1)];
        if (RELU) v = fmaxf(v, 0.f);
        G[i] = v;
    }
}

// logits = sigmoid(dot(enc[a], enc[b])) — 16 lanes per pair, 64 channels
__global__ void k_decode(const float* __restrict__ enc, const int* __restrict__ eli,
                         int M, float* __restrict__ out)
{
    int gid  = blockIdx.x * 256 + threadIdx.x;
    int pair = gid >> 4;
    int l    = gid & 15;
    if (pair >= M) return;
    int a = eli[pair];
    int b = eli[M + pair];
    float4 va = reinterpret_cast<const float4*>(enc + (size_t)a * 64)[l];
    float4 vb = reinterpret_cast<const float4*>(enc + (size_t)b * 64)[l];
    float s = va.x * vb.x + va.y * vb.y + va.z * vb.z + va.w * vb.w;
    s += __shfl_xor(s, 8, 16);
    s += __shfl_xor(s, 4, 16);
    s += __shfl_xor(s, 2, 16);
    s += __shfl_xor(s, 1, 16);
    if (l == 0) out[pair] = 1.f / (1.f + expf(-s));
}

extern "C" void kernel_launch(void* const* d_in, const int* in_sizes, int n_in,
                              void* d_out, int out_size, void* d_ws, size_t ws_size,
                              hipStream_t stream)
{
    const float* x     = (const float*)d_in[0];
    const int*   ei    = (const int*)d_in[1];
    const float* ew    = (const float*)d_in[2];
    const int*   eli   = (const int*)d_in[3];
    const float* W_in  = (const float*)d_in[4];
    const float* b_in  = (const float*)d_in[5];
    const float* W_hid = (const float*)d_in[6];
    const float* b_hid = (const float*)d_in[7];
    const float* W_out = (const float*)d_in[8];
    const float* b_out = (const float*)d_in[9];

    const int n = in_sizes[0] / 64;
    const int E = in_sizes[1] / 2;
    const int M = in_sizes[3] / 2;
    const int* row = ei;
    const int* col = ei + E;

    // workspace layout (floats): dinv[n] | norm[E] | B0[n*128] | B1[n*128]
    float* ws   = (float*)d_ws;
    float* dinv = ws;
    float* norm = ws + n;
    float* B0   = norm + E;                    // GEMM output H
    float* B1   = B0 + (size_t)n * 128;        // layer activation / aggregate

    const int nb_n = (n + 255) / 256;
    const int nb_E = (E + 255) / 256;
    const int gb   = (n + 15) / 16;
    const int sb   = (E + 3) / 4;
    const long nb128 = ((long)n * 128 + 255) / 256;
    const long nb64  = ((long)n * 64 + 255) / 256;

    // ---- gcn_norm ----
    k_init_deg<<<nb_n, 256, 0, stream>>>(dinv, n);
    k_accum_deg<<<nb_E, 256, 0, stream>>>(col, ew, dinv, E);
    k_dinv<<<nb_n, 256, 0, stream>>>(dinv, n);
    k_norm<<<nb_E, 256, 0, stream>>>(row, col, ew, dinv, norm, E);

    // ---- layer 1: 64 -> 128 (in = x, out = B1) ----
    k_gemm<64, 128><<<gb, 256, 0, stream>>>(x, W_in, B0, n);
    k_selfloop<128><<<(int)(((long)n * 32 + 255) / 256), 256, 0, stream>>>(B0, dinv, B1, n);
    k_scatter<128><<<sb, 256, 0, stream>>>(B0, row, col, norm, B1, E);
    k_bias_act<true, 128><<<(int)nb128, 256, 0, stream>>>(B1, b_in, n);

    // ---- 4 hidden layers: 128 -> 128 (in = B1, out = B1) ----
    for (int i = 0; i < 4; i++) {
        k_gemm<128, 128><<<gb, 256, 0, stream>>>(B1, W_hid + (size_t)i * 128 * 128, B0, n);
        k_selfloop<128><<<(int)(((long)n * 32 + 255) / 256), 256, 0, stream>>>(B0, dinv, B1, n);
        k_scatter<128><<<sb, 256, 0, stream>>>(B0, row, col, norm, B1, E);
        k_bias_act<true, 128><<<(int)nb128, 256, 0, stream>>>(B1, b_hid + (size_t)i * 128, n);
    }

    // ---- output layer: 128 -> 64 (in = B1, out = B1) ----
    k_gemm<128, 64><<<gb, 256, 0, stream>>>(B1, W_out, B0, n);
    k_selfloop<64><<<(int)(((long)n * 16 + 255) / 256), 256, 0, stream>>>(B0, dinv, B1, n);
    k_scatter<64><<<sb, 256, 0, stream>>>(B0, row, col, norm, B1, E);
    k_bias_act<false, 64><<<(int)nb64, 256, 0, stream>>>(B1, b_out, n);

    // ---- decoder ----
    k_decode<<<(M * 16 + 255) / 256, 256, 0, stream>>>(B1, eli, M, (float*)d_out);
}

// Round 3
// 1709.422 us; speedup vs baseline: 4.4959x; 4.4959x over previous
//
#include <hip/hip_runtime.h>
#include <hip/hip_bf16.h>
#include <math.h>

// ---------------------------------------------------------------------------
// GCN link-prediction encoder: 6 GCN layers + dot-product decoder.
// R3: replace per-edge atomic scatter (2.1 GB fabric traffic/layer) with a
// counting-sort CSR built once, then gather-aggregate per node with fused
// selfloop + bias + relu epilogue.
// ---------------------------------------------------------------------------

// deg[i] = 1 (self loop), hist[i] = 0
__global__ void k_init(float* __restrict__ deg, int* __restrict__ hist, int n) {
    int i = blockIdx.x * 256 + threadIdx.x;
    if (i < n) { deg[i] = 1.0f; hist[i] = 0; }
}

// deg[col] += ew ; hist[col] += 1
__global__ void k_edge_pass1(const int* __restrict__ col, const float* __restrict__ ew,
                             float* __restrict__ deg, int* __restrict__ hist, int E) {
    int i = blockIdx.x * 256 + threadIdx.x;
    if (i < E) {
        int c = col[i];
        unsafeAtomicAdd(&deg[c], ew[i]);
        atomicAdd(&hist[c], 1);
    }
}

__global__ void k_dinv(float* __restrict__ deg, int n) {
    int i = blockIdx.x * 256 + threadIdx.x;
    if (i < n) {
        float v = deg[i];
        deg[i] = (v > 0.f) ? rsqrtf(v) : 0.f;
    }
}

// ---- 3-kernel exclusive scan of hist -> rowptr ----
__global__ __launch_bounds__(256) void k_scan1(const int* __restrict__ hist,
                                               int* __restrict__ rowptr,
                                               int* __restrict__ bsum, int n) {
    __shared__ int lds[256];
    int t = threadIdx.x;
    int idx = blockIdx.x * 256 + t;
    int v = (idx < n) ? hist[idx] : 0;
    lds[t] = v; __syncthreads();
    for (int off = 1; off < 256; off <<= 1) {
        int x = (t >= off) ? lds[t - off] : 0;
        __syncthreads();
        lds[t] += x;
        __syncthreads();
    }
    if (idx < n) rowptr[idx] = lds[t] - v;     // local exclusive
    if (t == 255) bsum[blockIdx.x] = lds[255]; // block total
}

__global__ __launch_bounds__(256) void k_scan2(const int* __restrict__ bsum,
                                               int* __restrict__ boff, int nb,
                                               int* __restrict__ rowptr, int n) {
    __shared__ int lds[256];
    int t = threadIdx.x;
    int carry = 0;
    for (int base = 0; base < nb; base += 256) {
        int v = (base + t < nb) ? bsum[base + t] : 0;
        lds[t] = v; __syncthreads();
        for (int off = 1; off < 256; off <<= 1) {
            int x = (t >= off) ? lds[t - off] : 0;
            __syncthreads();
            lds[t] += x;
            __syncthreads();
        }
        if (base + t < nb) boff[base + t] = carry + lds[t] - v;  // exclusive
        carry += lds[255];
        __syncthreads();
    }
    if (t == 0) rowptr[n] = carry;   // == E
}

__global__ void k_scan3(int* __restrict__ rowptr, const int* __restrict__ boff,
                        int* __restrict__ cursor, int n) {
    int i = blockIdx.x * 256 + threadIdx.x;
    if (i < n) {
        int v = rowptr[i] + boff[blockIdx.x];
        rowptr[i] = v;
        cursor[i] = v;
    }
}

// place each edge into its col-sorted slot: pairs[pos] = {row, norm}
__global__ void k_sortscatter(const int* __restrict__ row, const int* __restrict__ col,
                              const float* __restrict__ ew, const float* __restrict__ dinv,
                              int* __restrict__ cursor, int2* __restrict__ pairs, int E) {
    int e = blockIdx.x * 256 + threadIdx.x;
    if (e >= E) return;
    int r = row[e], c = col[e];
    float nm = dinv[r] * ew[e] * dinv[c];
    int pos = atomicAdd(&cursor[c], 1);
    pairs[pos] = make_int2(r, __float_as_int(nm));
}

// H = X @ W   (X: [n, IN_C], W: [IN_C, OUT_C] row-major, H: [n, OUT_C])
template <int IN_C, int OUT_C>
__global__ __launch_bounds__(256) void k_gemm(
    const float* __restrict__ X, const float* __restrict__ W,
    float* __restrict__ H, int n)
{
    constexpr int C4  = OUT_C / 4;
    constexpr int RG  = 256 / C4;
    constexpr int RPT = 16 / RG;

    __shared__ float xs[16 * IN_C];
    const int row0 = blockIdx.x * 16;
    const int tid  = threadIdx.x;

    {
        const float4* X4  = reinterpret_cast<const float4*>(X + (size_t)row0 * IN_C);
        float4*       xs4 = reinterpret_cast<float4*>(xs);
        constexpr int NLD = 16 * IN_C / 4;
        #pragma unroll
        for (int i = tid; i < NLD; i += 256) {
            int r = i / (IN_C / 4);
            xs4[i] = (row0 + r < n) ? X4[i] : make_float4(0.f, 0.f, 0.f, 0.f);
        }
    }
    __syncthreads();

    const int c4 = tid % C4;
    const int rg = tid / C4;
    const float4* W4 = reinterpret_cast<const float4*>(W);

    float4 acc[RPT];
    #pragma unroll
    for (int j = 0; j < RPT; j++) acc[j] = make_float4(0.f, 0.f, 0.f, 0.f);

    for (int k = 0; k < IN_C; k++) {
        float4 w4 = W4[k * C4 + c4];
        #pragma unroll
        for (int j = 0; j < RPT; j++) {
            float xv = xs[(rg + j * RG) * IN_C + k];
            acc[j].x += xv * w4.x;
            acc[j].y += xv * w4.y;
            acc[j].z += xv * w4.z;
            acc[j].w += xv * w4.w;
        }
    }

    float4* H4 = reinterpret_cast<float4*>(H);
    #pragma unroll
    for (int j = 0; j < RPT; j++) {
        int r = row0 + rg + j * RG;
        if (r < n) H4[(size_t)r * C4 + c4] = acc[j];
    }
}

// Out[c] = act( dinv[c]^2*H[c] + sum_e norm[e]*H[row[e]] + bias )
// one wave per node; 64 lanes span OC channels.
template <bool RELU, int OC>
__global__ __launch_bounds__(256) void k_aggregate(
    const float* __restrict__ H, const int2* __restrict__ pairs,
    const int* __restrict__ rowptr, const float* __restrict__ dinv,
    const float* __restrict__ bias, float* __restrict__ Out, int n)
{
    const int lane = threadIdx.x & 63;
    const int w    = threadIdx.x >> 6;
    int nd = blockIdx.x * 4 + w;
    if (nd >= n) return;
    int s  = rowptr[nd];
    int en = rowptr[nd + 1];
    float d  = dinv[nd];
    float d2 = d * d;

    if constexpr (OC == 128) {
        const float2* H2 = reinterpret_cast<const float2*>(H);
        float2 h = H2[(size_t)nd * 64 + lane];
        float2 acc = make_float2(d2 * h.x, d2 * h.y);
        int e = s;
        for (; e + 1 < en; e += 2) {       // 2-deep to overlap gather latency
            int2 p0 = pairs[e];
            int2 p1 = pairs[e + 1];
            float2 v0 = H2[(size_t)p0.x * 64 + lane];
            float2 v1 = H2[(size_t)p1.x * 64 + lane];
            float n0 = __int_as_float(p0.y), n1 = __int_as_float(p1.y);
            acc.x += n0 * v0.x; acc.y += n0 * v0.y;
            acc.x += n1 * v1.x; acc.y += n1 * v1.y;
        }
        if (e < en) {
            int2 p = pairs[e];
            float2 v = H2[(size_t)p.x * 64 + lane];
            float nm = __int_as_float(p.y);
            acc.x += nm * v.x; acc.y += nm * v.y;
        }
        float2 bb = reinterpret_cast<const float2*>(bias)[lane];
        acc.x += bb.x; acc.y += bb.y;
        if (RELU) { acc.x = fmaxf(acc.x, 0.f); acc.y = fmaxf(acc.y, 0.f); }
        reinterpret_cast<float2*>(Out)[(size_t)nd * 64 + lane] = acc;
    } else {
        float acc = d2 * H[(size_t)nd * 64 + lane];
        int e = s;
        for (; e + 1 < en; e += 2) {
            int2 p0 = pairs[e];
            int2 p1 = pairs[e + 1];
            float v0 = H[(size_t)p0.x * 64 + lane];
            float v1 = H[(size_t)p1.x * 64 + lane];
            acc += __int_as_float(p0.y) * v0;
            acc += __int_as_float(p1.y) * v1;
        }
        if (e < en) {
            int2 p = pairs[e];
            acc += __int_as_float(p.y) * H[(size_t)p.x * 64 + lane];
        }
        acc += bias[lane];
        if (RELU) acc = fmaxf(acc, 0.f);
        Out[(size_t)nd * 64 + lane] = acc;
    }
}

// logits = sigmoid(dot(enc[a], enc[b])) — 16 lanes per pair, 64 channels
__global__ void k_decode(const float* __restrict__ enc, const int* __restrict__ eli,
                         int M, float* __restrict__ out)
{
    int gid  = blockIdx.x * 256 + threadIdx.x;
    int pair = gid >> 4;
    int l    = gid & 15;
    if (pair >= M) return;
    int a = eli[pair];
    int b = eli[M + pair];
    float4 va = reinterpret_cast<const float4*>(enc + (size_t)a * 64)[l];
    float4 vb = reinterpret_cast<const float4*>(enc + (size_t)b * 64)[l];
    float s = va.x * vb.x + va.y * vb.y + va.z * vb.z + va.w * vb.w;
    s += __shfl_xor(s, 8, 16);
    s += __shfl_xor(s, 4, 16);
    s += __shfl_xor(s, 2, 16);
    s += __shfl_xor(s, 1, 16);
    if (l == 0) out[pair] = 1.f / (1.f + expf(-s));
}

extern "C" void kernel_launch(void* const* d_in, const int* in_sizes, int n_in,
                              void* d_out, int out_size, void* d_ws, size_t ws_size,
                              hipStream_t stream)
{
    const float* x     = (const float*)d_in[0];
    const int*   ei    = (const int*)d_in[1];
    const float* ew    = (const float*)d_in[2];
    const int*   eli   = (const int*)d_in[3];
    const float* W_in  = (const float*)d_in[4];
    const float* b_in  = (const float*)d_in[5];
    const float* W_hid = (const float*)d_in[6];
    const float* b_hid = (const float*)d_in[7];
    const float* W_out = (const float*)d_in[8];
    const float* b_out = (const float*)d_in[9];

    const int n = in_sizes[0] / 64;
    const int E = in_sizes[1] / 2;
    const int M = in_sizes[3] / 2;
    const int* row = ei;
    const int* col = ei + E;

    const int NB = (n + 255) / 256;

    // workspace layout (4-byte units, all regions multiple-of-4 so pairs is
    // 8B-aligned and B0/B1 are 16B-aligned):
    // dinv[n] | hist[n] | rowptr[n+4] | cursor[n] | bsum[1024] | boff[1024]
    // | pairs[2E] | B0[n*128] | B1[n*128]
    float* ws     = (float*)d_ws;
    float* dinv   = ws;                         // doubles as deg before k_dinv
    int*   hist   = (int*)(dinv + n);
    int*   rowptr = hist + n;
    int*   cursor = rowptr + n + 4;
    int*   bsum   = cursor + n;
    int*   boff   = bsum + 1024;
    int2*  pairs  = (int2*)(boff + 1024);
    float* B0     = (float*)(pairs + E);        // GEMM output H
    float* B1     = B0 + (size_t)n * 128;       // aggregated activation

    const int nb_n = NB;
    const int nb_E = (E + 255) / 256;
    const int gb   = (n + 15) / 16;
    const int ab   = (n + 3) / 4;

    // ---- norm + CSR build (shared by all layers) ----
    k_init<<<nb_n, 256, 0, stream>>>(dinv, hist, n);
    k_edge_pass1<<<nb_E, 256, 0, stream>>>(col, ew, dinv, hist, E);
    k_dinv<<<nb_n, 256, 0, stream>>>(dinv, n);
    k_scan1<<<NB, 256, 0, stream>>>(hist, rowptr, bsum, n);
    k_scan2<<<1, 256, 0, stream>>>(bsum, boff, NB, rowptr, n);
    k_scan3<<<NB, 256, 0, stream>>>(rowptr, boff, cursor, n);
    k_sortscatter<<<nb_E, 256, 0, stream>>>(row, col, ew, dinv, cursor, pairs, E);

    // ---- layer 1: 64 -> 128 ----
    k_gemm<64, 128><<<gb, 256, 0, stream>>>(x, W_in, B0, n);
    k_aggregate<true, 128><<<ab, 256, 0, stream>>>(B0, pairs, rowptr, dinv, b_in, B1, n);

    // ---- 4 hidden layers: 128 -> 128 ----
    for (int i = 0; i < 4; i++) {
        k_gemm<128, 128><<<gb, 256, 0, stream>>>(B1, W_hid + (size_t)i * 128 * 128, B0, n);
        k_aggregate<true, 128><<<ab, 256, 0, stream>>>(B0, pairs, rowptr, dinv,
                                                       b_hid + (size_t)i * 128, B1, n);
    }

    // ---- output layer: 128 -> 64 ----
    k_gemm<128, 64><<<gb, 256, 0, stream>>>(B1, W_out, B0, n);
    k_aggregate<false, 64><<<ab, 256, 0, stream>>>(B0, pairs, rowptr, dinv, b_out, B1, n);

    // ---- decoder ----
    k_decode<<<(M * 16 + 255) / 256, 256, 0, stream>>>(B1, eli, M, (float*)d_out);
}

// Round 4
// 831.590 us; speedup vs baseline: 9.2417x; 2.0556x over previous
//
#include <hip/hip_runtime.h>
#include <hip/hip_bf16.h>
#include <math.h>

// ---------------------------------------------------------------------------
// GCN link-prediction encoder: 6 GCN layers + dot-product decoder.
// R4: bf16 everywhere it counts — MFMA GEMM (bf16 in, f32 acc) and bf16 H
// for the gather-aggregate (halves gather bytes). CSR built once (R3).
// ---------------------------------------------------------------------------

using bf16x8 = __attribute__((ext_vector_type(8))) short;  // 8 bf16 = 4 VGPRs
using f32x4  = __attribute__((ext_vector_type(4))) float;

__device__ inline unsigned f2bf_bits(float f) {            // RNE f32 -> bf16
    unsigned u = __float_as_uint(f);
    return (u + 0x7fffu + ((u >> 16) & 1u)) >> 16;
}
__device__ inline float bflo(unsigned w) { return __uint_as_float(w << 16); }
__device__ inline float bfhi(unsigned w) { return __uint_as_float(w & 0xffff0000u); }

// ---------------- CSR + norm build (unchanged from R3) ----------------

__global__ void k_init(float* __restrict__ deg, int* __restrict__ hist, int n) {
    int i = blockIdx.x * 256 + threadIdx.x;
    if (i < n) { deg[i] = 1.0f; hist[i] = 0; }
}

__global__ void k_edge_pass1(const int* __restrict__ col, const float* __restrict__ ew,
                             float* __restrict__ deg, int* __restrict__ hist, int E) {
    int i = blockIdx.x * 256 + threadIdx.x;
    if (i < E) {
        int c = col[i];
        unsafeAtomicAdd(&deg[c], ew[i]);
        atomicAdd(&hist[c], 1);
    }
}

__global__ void k_dinv(float* __restrict__ deg, int n) {
    int i = blockIdx.x * 256 + threadIdx.x;
    if (i < n) {
        float v = deg[i];
        deg[i] = (v > 0.f) ? rsqrtf(v) : 0.f;
    }
}

__global__ __launch_bounds__(256) void k_scan1(const int* __restrict__ hist,
                                               int* __restrict__ rowptr,
                                               int* __restrict__ bsum, int n) {
    __shared__ int lds[256];
    int t = threadIdx.x;
    int idx = blockIdx.x * 256 + t;
    int v = (idx < n) ? hist[idx] : 0;
    lds[t] = v; __syncthreads();
    for (int off = 1; off < 256; off <<= 1) {
        int x = (t >= off) ? lds[t - off] : 0;
        __syncthreads();
        lds[t] += x;
        __syncthreads();
    }
    if (idx < n) rowptr[idx] = lds[t] - v;
    if (t == 255) bsum[blockIdx.x] = lds[255];
}

__global__ __launch_bounds__(256) void k_scan2(const int* __restrict__ bsum,
                                               int* __restrict__ boff, int nb,
                                               int* __restrict__ rowptr, int n) {
    __shared__ int lds[256];
    int t = threadIdx.x;
    int carry = 0;
    for (int base = 0; base < nb; base += 256) {
        int v = (base + t < nb) ? bsum[base + t] : 0;
        lds[t] = v; __syncthreads();
        for (int off = 1; off < 256; off <<= 1) {
            int x = (t >= off) ? lds[t - off] : 0;
            __syncthreads();
            lds[t] += x;
            __syncthreads();
        }
        if (base + t < nb) boff[base + t] = carry + lds[t] - v;
        carry += lds[255];
        __syncthreads();
    }
    if (t == 0) rowptr[n] = carry;
}

__global__ void k_scan3(int* __restrict__ rowptr, const int* __restrict__ boff,
                        int* __restrict__ cursor, int n) {
    int i = blockIdx.x * 256 + threadIdx.x;
    if (i < n) {
        int v = rowptr[i] + boff[blockIdx.x];
        rowptr[i] = v;
        cursor[i] = v;
    }
}

__global__ void k_sortscatter(const int* __restrict__ row, const int* __restrict__ col,
                              const float* __restrict__ ew, const float* __restrict__ dinv,
                              int* __restrict__ cursor, int2* __restrict__ pairs, int E) {
    int e = blockIdx.x * 256 + threadIdx.x;
    if (e >= E) return;
    int r = row[e], c = col[e];
    float nm = dinv[r] * ew[e] * dinv[c];
    int pos = atomicAdd(&cursor[c], 1);
    pairs[pos] = make_int2(r, __float_as_int(nm));
}

// ---------------- weight prep: W[K][N] f32 -> Wt[N][K] bf16 ----------------

__global__ void k_wt(const float* __restrict__ W, unsigned short* __restrict__ wt,
                     int K, int N) {
    int i = blockIdx.x * 256 + threadIdx.x;
    if (i >= K * N) return;
    int k = i / N, nn = i % N;
    wt[nn * K + k] = (unsigned short)f2bf_bits(W[i]);
}

// ---------------- MFMA GEMM: H = X @ W, bf16 in, f32 acc, bf16 out --------
// 128-row tile, 256 threads = 4 waves, wave w does rows [w*32, w*32+32).
// X and Wt staged in LDS (bf16, XOR-swizzled: byte ^= (row&7)<<4).
// Fragment layout (gfx950 16x16x32 bf16):
//   A: lane l holds A[l&15][(l>>4)*8 + j]   (ds_read_b128 from row-major X)
//   B: lane l holds B[(l>>4)*8 + j][l&15]   (ds_read_b128 from Wt[N][K])
//   D: reg r -> D[(l>>4)*4 + r][l&15]       (m89-verified)
template <int K, int N, bool IN_BF16>
__global__ __launch_bounds__(256, 2) void k_gemm_mfma(
    const void* __restrict__ Xv, const unsigned short* __restrict__ Wt,
    unsigned short* __restrict__ H, int n)
{
    constexpr int NREP = N / 16;
    constexpr int KC   = K / 8;          // 16B chunks per row
    __shared__ char lds[128 * K * 2 + N * K * 2];
    char* Xs = lds;
    char* Ws = lds + 128 * K * 2;

    const int row0 = blockIdx.x * 128;
    const int tid  = threadIdx.x;

    // stage X tile (convert f32->bf16 if needed), swizzled
    for (int c = tid; c < 128 * KC; c += 256) {
        int r = c / KC, kc = c % KC;
        int gr = row0 + r;
        bf16x8 v = {0, 0, 0, 0, 0, 0, 0, 0};
        if (gr < n) {
            if constexpr (IN_BF16) {
                v = *(const bf16x8*)((const unsigned short*)Xv + (size_t)gr * K + kc * 8);
            } else {
                const float* xp = (const float*)Xv + (size_t)gr * K + kc * 8;
                float4 a = *(const float4*)xp;
                float4 b = *(const float4*)(xp + 4);
                v[0] = (short)f2bf_bits(a.x); v[1] = (short)f2bf_bits(a.y);
                v[2] = (short)f2bf_bits(a.z); v[3] = (short)f2bf_bits(a.w);
                v[4] = (short)f2bf_bits(b.x); v[5] = (short)f2bf_bits(b.y);
                v[6] = (short)f2bf_bits(b.z); v[7] = (short)f2bf_bits(b.w);
            }
        }
        *(bf16x8*)(Xs + ((r * (K * 2) + kc * 16) ^ ((r & 7) << 4))) = v;
    }
    // stage Wt (already bf16, [N][K]), swizzled
    for (int c = tid; c < N * KC; c += 256) {
        int r = c / KC, kc = c % KC;
        bf16x8 v = *(const bf16x8*)(Wt + (size_t)r * K + kc * 8);
        *(bf16x8*)(Ws + ((r * (K * 2) + kc * 16) ^ ((r & 7) << 4))) = v;
    }
    __syncthreads();

    const int wv   = tid >> 6;
    const int lane = tid & 63;
    const int lr   = lane & 15;
    const int lk   = lane >> 4;

    f32x4 acc[2][NREP];
    #pragma unroll
    for (int m = 0; m < 2; m++)
        #pragma unroll
        for (int j = 0; j < NREP; j++)
            acc[m][j] = (f32x4){0.f, 0.f, 0.f, 0.f};

    #pragma unroll
    for (int kk = 0; kk < K / 32; kk++) {
        int kc = kk * 4 + lk;            // 16B chunk index of this lane's k0
        bf16x8 af[2];
        #pragma unroll
        for (int m = 0; m < 2; m++) {
            int r = wv * 32 + m * 16 + lr;
            af[m] = *(const bf16x8*)(Xs + ((r * (K * 2) + kc * 16) ^ ((r & 7) << 4)));
        }
        #pragma unroll
        for (int j = 0; j < NREP; j++) {
            int r = j * 16 + lr;
            bf16x8 bfr = *(const bf16x8*)(Ws + ((r * (K * 2) + kc * 16) ^ ((r & 7) << 4)));
            acc[0][j] = __builtin_amdgcn_mfma_f32_16x16x32_bf16(af[0], bfr, acc[0][j], 0, 0, 0);
            acc[1][j] = __builtin_amdgcn_mfma_f32_16x16x32_bf16(af[1], bfr, acc[1][j], 0, 0, 0);
        }
    }

    // epilogue: D[(lk*4+r)][lr] -> H bf16
    #pragma unroll
    for (int m = 0; m < 2; m++) {
        #pragma unroll
        for (int j = 0; j < NREP; j++) {
            #pragma unroll
            for (int rr = 0; rr < 4; rr++) {
                int gr = row0 + wv * 32 + m * 16 + lk * 4 + rr;
                if (gr < n)
                    H[(size_t)gr * N + j * 16 + lr] = (unsigned short)f2bf_bits(acc[m][j][rr]);
            }
        }
    }
}

// ---------------- gather-aggregate: bf16 H in, fused selfloop+bias+act ----
// Out[c] = act( dinv[c]^2*H[c] + sum_e norm[e]*H[row[e]] + bias )
template <bool RELU, int OC, bool OUTBF>
__global__ __launch_bounds__(256) void k_aggregate(
    const unsigned short* __restrict__ H, const int2* __restrict__ pairs,
    const int* __restrict__ rowptr, const float* __restrict__ dinv,
    const float* __restrict__ bias, void* __restrict__ Out, int n)
{
    const int lane = threadIdx.x & 63;
    const int w    = threadIdx.x >> 6;
    int nd = blockIdx.x * 4 + w;
    if (nd >= n) return;
    int s  = rowptr[nd];
    int en = rowptr[nd + 1];
    float d  = dinv[nd];
    float d2 = d * d;

    if constexpr (OC == 128) {
        const unsigned* Hu = (const unsigned*)H;   // 2 bf16 per uint
        unsigned sw = Hu[(size_t)nd * 64 + lane];
        float ax = d2 * bflo(sw), ay = d2 * bfhi(sw);
        int e = s;
        for (; e + 3 < en; e += 4) {               // 4-deep for MLP latency
            int2 p0 = pairs[e],     p1 = pairs[e + 1];
            int2 p2 = pairs[e + 2], p3 = pairs[e + 3];
            unsigned w0 = Hu[(size_t)p0.x * 64 + lane];
            unsigned w1 = Hu[(size_t)p1.x * 64 + lane];
            unsigned w2 = Hu[(size_t)p2.x * 64 + lane];
            unsigned w3 = Hu[(size_t)p3.x * 64 + lane];
            float n0 = __int_as_float(p0.y), n1 = __int_as_float(p1.y);
            float n2 = __int_as_float(p2.y), n3 = __int_as_float(p3.y);
            ax = fmaf(n0, bflo(w0), ax); ay = fmaf(n0, bfhi(w0), ay);
            ax = fmaf(n1, bflo(w1), ax); ay = fmaf(n1, bfhi(w1), ay);
            ax = fmaf(n2, bflo(w2), ax); ay = fmaf(n2, bfhi(w2), ay);
            ax = fmaf(n3, bflo(w3), ax); ay = fmaf(n3, bfhi(w3), ay);
        }
        for (; e < en; e++) {
            int2 p = pairs[e];
            unsigned ww = Hu[(size_t)p.x * 64 + lane];
            float nm = __int_as_float(p.y);
            ax = fmaf(nm, bflo(ww), ax); ay = fmaf(nm, bfhi(ww), ay);
        }
        float2 bb = reinterpret_cast<const float2*>(bias)[lane];
        ax += bb.x; ay += bb.y;
        if (RELU) { ax = fmaxf(ax, 0.f); ay = fmaxf(ay, 0.f); }
        if constexpr (OUTBF) {
            ((unsigned*)Out)[(size_t)nd * 64 + lane] =
                f2bf_bits(ax) | (f2bf_bits(ay) << 16);
        } else {
            ((float2*)Out)[(size_t)nd * 64 + lane] = make_float2(ax, ay);
        }
    } else {  // OC == 64
        float acc = d2 * bflo((unsigned)H[(size_t)nd * 64 + lane] << 0) ;
        acc = d2 * __uint_as_float(((unsigned)H[(size_t)nd * 64 + lane]) << 16);
        int e = s;
        for (; e + 3 < en; e += 4) {
            int2 p0 = pairs[e],     p1 = pairs[e + 1];
            int2 p2 = pairs[e + 2], p3 = pairs[e + 3];
            float v0 = __uint_as_float(((unsigned)H[(size_t)p0.x * 64 + lane]) << 16);
            float v1 = __uint_as_float(((unsigned)H[(size_t)p1.x * 64 + lane]) << 16);
            float v2 = __uint_as_float(((unsigned)H[(size_t)p2.x * 64 + lane]) << 16);
            float v3 = __uint_as_float(((unsigned)H[(size_t)p3.x * 64 + lane]) << 16);
            acc = fmaf(__int_as_float(p0.y), v0, acc);
            acc = fmaf(__int_as_float(p1.y), v1, acc);
            acc = fmaf(__int_as_float(p2.y), v2, acc);
            acc = fmaf(__int_as_float(p3.y), v3, acc);
        }
        for (; e < en; e++) {
            int2 p = pairs[e];
            acc = fmaf(__int_as_float(p.y),
                       __uint_as_float(((unsigned)H[(size_t)p.x * 64 + lane]) << 16), acc);
        }
        acc += bias[lane];
        if (RELU) acc = fmaxf(acc, 0.f);
        ((float*)Out)[(size_t)nd * 64 + lane] = acc;   // enc stays f32
    }
}

// logits = sigmoid(dot(enc[a], enc[b])) — 16 lanes per pair, 64 channels
__global__ void k_decode(const float* __restrict__ enc, const int* __restrict__ eli,
                         int M, float* __restrict__ out)
{
    int gid  = blockIdx.x * 256 + threadIdx.x;
    int pair = gid >> 4;
    int l    = gid & 15;
    if (pair >= M) return;
    int a = eli[pair];
    int b = eli[M + pair];
    float4 va = reinterpret_cast<const float4*>(enc + (size_t)a * 64)[l];
    float4 vb = reinterpret_cast<const float4*>(enc + (size_t)b * 64)[l];
    float s = va.x * vb.x + va.y * vb.y + va.z * vb.z + va.w * vb.w;
    s += __shfl_xor(s, 8, 16);
    s += __shfl_xor(s, 4, 16);
    s += __shfl_xor(s, 2, 16);
    s += __shfl_xor(s, 1, 16);
    if (l == 0) out[pair] = 1.f / (1.f + expf(-s));
}

extern "C" void kernel_launch(void* const* d_in, const int* in_sizes, int n_in,
                              void* d_out, int out_size, void* d_ws, size_t ws_size,
                              hipStream_t stream)
{
    const float* x     = (const float*)d_in[0];
    const int*   ei    = (const int*)d_in[1];
    const float* ew    = (const float*)d_in[2];
    const int*   eli   = (const int*)d_in[3];
    const float* W_in  = (const float*)d_in[4];
    const float* b_in  = (const float*)d_in[5];
    const float* W_hid = (const float*)d_in[6];
    const float* b_hid = (const float*)d_in[7];
    const float* W_out = (const float*)d_in[8];
    const float* b_out = (const float*)d_in[9];

    const int n = in_sizes[0] / 64;
    const int E = in_sizes[1] / 2;
    const int M = in_sizes[3] / 2;
    const int* row = ei;
    const int* col = ei + E;

    const int NB = (n + 255) / 256;

    // ---- workspace layout (bytes, 256-aligned regions) ----
    char* base = (char*)d_ws;
    size_t off = 0;
    auto alloc = [&](size_t bytes) { char* p = base + off; off = (off + bytes + 255) & ~(size_t)255; return p; };
    float* dinv   = (float*)alloc((size_t)n * 4);
    int*   hist   = (int*)  alloc((size_t)n * 4);
    int*   rowptr = (int*)  alloc((size_t)(n + 1) * 4);
    int*   cursor = (int*)  alloc((size_t)n * 4);
    int*   bsum   = (int*)  alloc(1024 * 4);
    int*   boff   = (int*)  alloc(1024 * 4);
    int2*  pairs  = (int2*) alloc((size_t)E * 8);
    unsigned short* wt_in  = (unsigned short*)alloc((size_t)128 * 64 * 2);
    unsigned short* wt_hid = (unsigned short*)alloc((size_t)4 * 128 * 128 * 2);
    unsigned short* wt_out = (unsigned short*)alloc((size_t)64 * 128 * 2);
    unsigned short* Hbf    = (unsigned short*)alloc((size_t)n * 128 * 2);  // GEMM out
    unsigned short* Abf    = (unsigned short*)alloc((size_t)n * 128 * 2);  // activations
    float*          enc    = (float*)alloc((size_t)n * 64 * 4);

    const int nb_E = (E + 255) / 256;
    const int gb   = (n + 127) / 128;
    const int ab   = (n + 3) / 4;

    // ---- norm + CSR build (shared by all layers) ----
    k_init<<<NB, 256, 0, stream>>>(dinv, hist, n);
    k_edge_pass1<<<nb_E, 256, 0, stream>>>(col, ew, dinv, hist, E);
    k_dinv<<<NB, 256, 0, stream>>>(dinv, n);
    k_scan1<<<NB, 256, 0, stream>>>(hist, rowptr, bsum, n);
    k_scan2<<<1, 256, 0, stream>>>(bsum, boff, NB, rowptr, n);
    k_scan3<<<NB, 256, 0, stream>>>(rowptr, boff, cursor, n);
    k_sortscatter<<<nb_E, 256, 0, stream>>>(row, col, ew, dinv, cursor, pairs, E);

    // ---- weight prep (f32 -> bf16, transposed [N][K]) ----
    k_wt<<<(64 * 128 + 255) / 256, 256, 0, stream>>>(W_in, wt_in, 64, 128);
    for (int i = 0; i < 4; i++)
        k_wt<<<(128 * 128 + 255) / 256, 256, 0, stream>>>(
            W_hid + (size_t)i * 128 * 128, wt_hid + (size_t)i * 128 * 128, 128, 128);
    k_wt<<<(128 * 64 + 255) / 256, 256, 0, stream>>>(W_out, wt_out, 128, 64);

    // ---- layer 1: 64 -> 128 (x f32 in) ----
    k_gemm_mfma<64, 128, false><<<gb, 256, 0, stream>>>(x, wt_in, Hbf, n);
    k_aggregate<true, 128, true><<<ab, 256, 0, stream>>>(Hbf, pairs, rowptr, dinv, b_in, Abf, n);

    // ---- 4 hidden layers: 128 -> 128 ----
    for (int i = 0; i < 4; i++) {
        k_gemm_mfma<128, 128, true><<<gb, 256, 0, stream>>>(
            Abf, wt_hid + (size_t)i * 128 * 128, Hbf, n);
        k_aggregate<true, 128, true><<<ab, 256, 0, stream>>>(
            Hbf, pairs, rowptr, dinv, b_hid + (size_t)i * 128, Abf, n);
    }

    // ---- output layer: 128 -> 64 ----
    k_gemm_mfma<128, 64, true><<<gb, 256, 0, stream>>>(Abf, wt_out, Hbf, n);
    k_aggregate<false, 64, false><<<ab, 256, 0, stream>>>(
        Hbf, pairs, rowptr, dinv, b_out, enc, n);

    // ---- decoder ----
    k_decode<<<(M * 16 + 255) / 256, 256, 0, stream>>>(enc, eli, M, (float*)d_out);
}